// Round 1
// baseline (77.411 us; speedup 1.0000x reference)
//
#include <hip/hip_runtime.h>
#include <stdint.h>

#define N_ 8192
#define D_ 64
#define M_ 3
#define ROWS 64      // output rows per block
#define CROWS 66     // coefficient rows j in [0,66): need d/o at i, i+1, i+2
#define WPAD 68      // staged Wf columns per (m,d), padded/rounded to 17 float4 groups

typedef __attribute__((ext_vector_type(8))) short short8;
typedef __attribute__((ext_vector_type(8))) __bf16 bf16x8;
typedef __attribute__((ext_vector_type(4))) float f32x4;

// float -> bf16 (round-to-nearest-even) on raw bits
__device__ __forceinline__ short f2bf(float f) {
    uint32_t u = __builtin_bit_cast(uint32_t, f);
    u = (u + 0x7FFFu + ((u >> 16) & 1u)) >> 16;
    return (short)(u & 0xFFFFu);
}

__device__ __forceinline__ f32x4 mfma16x16x32(short8 a, short8 b, f32x4 c) {
    return __builtin_amdgcn_mfma_f32_16x16x32_bf16(
        __builtin_bit_cast(bf16x8, a), __builtin_bit_cast(bf16x8, b), c, 0, 0, 0);
}

__global__ __launch_bounds__(256, 1) void smf_kernel(
    const float* __restrict__ X,    // [B][N][64]
    const float* __restrict__ Wg,   // [64][64]
    const float* __restrict__ bg,   // [64]
    const float* __restrict__ Wf,   // [3][64][N]
    const float* __restrict__ bfv,  // [3][N]
    float* __restrict__ Out)        // [B][N][64]
{
    __shared__ __align__(16) float Wfs[M_][D_][WPAD];   // 52224 B
    __shared__ float dd[M_][CROWS + 2];
    __shared__ float oo[M_][CROWS + 2];
    __shared__ float cks[5][ROWS];                      // c0..c3, csum

    const int tid = threadIdx.x;
    const int bid = blockIdx.x;
    const int b   = bid & 1;          // adjacent blocks share the Wf chunk (L3 reuse)
    const int r0  = (bid >> 1) * ROWS;
    const float* Xb = X + (size_t)b * N_ * D_;

    const int l  = tid & 63;
    const int w  = tid >> 6;   // wave id 0..3 = output tile-row
    const int lo = l & 15;
    const int q  = l >> 4;

    // ---- prefetch phase-1 X row (exact fp32 coefficient dots) ----
    f32x4 xp1[16];
    int m1 = 0, j1 = 0, gi = 0, gi1 = 0;
    float pbd = 0.f, pbo = 0.f;
    const bool coefActive = (tid < M_ * CROWS);
    if (coefActive) {
        m1 = tid / CROWS;
        j1 = tid - m1 * CROWS;
        gi = r0 + j1;  if (gi  >= N_) gi  -= N_;
        gi1 = gi + 1;  if (gi1 >= N_) gi1 -= N_;
        const float* xrow = Xb + (size_t)gi * D_;
        #pragma unroll
        for (int g = 0; g < 16; ++g) xp1[g] = *(const f32x4*)(xrow + 4 * g);
        pbd = bfv[m1 * N_ + gi];
        pbo = bfv[m1 * N_ + gi1];
    }

    // ---- prefetch phase-3 X fragments (rows arow..arow+3, cols per MFMA A layout) ----
    const int arow = w * 16 + lo;  // local Y row this lane builds
    f32x4 xp3[2][4][2];
    #pragma unroll
    for (int kh = 0; kh < 2; ++kh) {
        #pragma unroll
        for (int k = 0; k < 4; ++k) {
            int gr = r0 + arow + k; if (gr >= N_) gr -= N_;
            const float* xr = Xb + (size_t)gr * D_ + kh * 32 + q * 8;
            xp3[kh][k][0] = *(const f32x4*)xr;
            xp3[kh][k][1] = *(const f32x4*)(xr + 4);
        }
    }

    // ---- B fragments (Wg, bf16) held in registers: f = te*2 + kh ----
    short8 Bfrag[8];
    #pragma unroll
    for (int te = 0; te < 4; ++te) {
        #pragma unroll
        for (int kh = 0; kh < 2; ++kh) {
            short8 s;
            #pragma unroll
            for (int jj = 0; jj < 8; ++jj) {
                int k = kh * 32 + q * 8 + jj;       // B[k][n]: n = lane&15
                s[jj] = f2bf(Wg[k * 64 + te * 16 + lo]);
            }
            Bfrag[te * 2 + kh] = s;
        }
    }

    // ---- stage Wf chunk (3 x 64 x 68 cols) into LDS, vectorized ----
    for (int p = tid; p < M_ * D_ * 17; p += 256) {
        int m   = p / (D_ * 17);
        int rem = p - m * (D_ * 17);
        int d   = rem / 17;
        int c4  = rem - d * 17;
        int col = (r0 + c4 * 4) & (N_ - 1);   // whole group wraps together (r0 is 64-aligned)
        f32x4 v = *(const f32x4*)(Wf + ((size_t)(m * D_ + d)) * N_ + col);
        *(f32x4*)&Wfs[m][d][c4 * 4] = v;
    }
    __syncthreads();

    // ---- phase 1: d_m, o_m coefficient dots (fp32 exact) ----
    if (coefActive) {
        float accd = pbd, acco = pbo;
        #pragma unroll
        for (int g = 0; g < 16; ++g) {
            #pragma unroll
            for (int k = 0; k < 4; ++k) {
                int d = g * 4 + k;
                float x = xp1[g][k];
                accd += x * Wfs[m1][d][j1];
                acco += x * Wfs[m1][d][j1 + 1];
            }
        }
        dd[m1][j1] = accd;
        oo[m1][j1] = acco;
    }
    __syncthreads();

    // ---- phase 2: path-product chain coefficients ----
    if (tid < ROWS) {
        int j = tid;
        float D0 = dd[0][j],   D1 = dd[1][j],   D2 = dd[2][j];
        float O0 = oo[0][j],   O1 = oo[1][j],   O2 = oo[2][j];
        float D0p = dd[0][j+1], D1p = dd[1][j+1];
        float O0p = oo[0][j+1], O1p = oo[1][j+1];
        float D0q = dd[0][j+2], O0q = oo[0][j+2];
        float c0 = D2 * D1 * D0;
        float c1 = D2 * D1 * O0 + D2 * O1 * D0p + O2 * D1p * D0p;
        float c2 = D2 * O1 * O0p + O2 * D1p * O0p + O2 * O1p * D0q;
        float c3 = O2 * O1p * O0q;
        cks[0][j] = c0; cks[1][j] = c1; cks[2][j] = c2; cks[3][j] = c3;
        cks[4][j] = c0 + c1 + c2 + c3;
    }
    __syncthreads();

    // ---- phase 3: Y = sum_k c_k * X[i+k] (fp32, in A-frag layout) -> MFMA -> epilogue ----
    float c[4];
    #pragma unroll
    for (int k = 0; k < 4; ++k) c[k] = cks[k][arow];

    f32x4 acc[4];
    #pragma unroll
    for (int te = 0; te < 4; ++te) acc[te] = (f32x4){0.f, 0.f, 0.f, 0.f};

    #pragma unroll
    for (int kh = 0; kh < 2; ++kh) {
        float y[8];
        #pragma unroll
        for (int jj = 0; jj < 8; ++jj) y[jj] = 0.f;
        #pragma unroll
        for (int k = 0; k < 4; ++k) {
            #pragma unroll
            for (int t = 0; t < 4; ++t) {
                y[t]     += c[k] * xp3[kh][k][0][t];
                y[4 + t] += c[k] * xp3[kh][k][1][t];
            }
        }
        short8 A;
        #pragma unroll
        for (int jj = 0; jj < 8; ++jj) A[jj] = f2bf(y[jj]);
        #pragma unroll
        for (int te = 0; te < 4; ++te)
            acc[te] = mfma16x16x32(A, Bfrag[te * 2 + kh], acc[te]);
    }

    // C/D layout: col = lane&15, row = (lane>>4)*4 + reg
    #pragma unroll
    for (int te = 0; te < 4; ++te) {
        #pragma unroll
        for (int r = 0; r < 4; ++r) {
            int orow = w * 16 + q * 4 + r;
            float v = acc[te][r] + cks[4][orow] * bg[te * 16 + lo];
            Out[((size_t)b * N_ + (r0 + orow)) * D_ + te * 16 + lo] = v;
        }
    }
}

extern "C" void kernel_launch(void* const* d_in, const int* in_sizes, int n_in,
                              void* d_out, int out_size, void* d_ws, size_t ws_size,
                              hipStream_t stream) {
    const float* X   = (const float*)d_in[0];
    const float* Wg  = (const float*)d_in[1];
    const float* bg  = (const float*)d_in[2];
    const float* Wf  = (const float*)d_in[3];
    const float* bfv = (const float*)d_in[4];
    float* Out = (float*)d_out;

    dim3 grid(2 * (N_ / ROWS));   // 256 blocks: (chunk, b) with b = bid&1
    dim3 block(256);
    hipLaunchKernelGGL(smf_kernel, grid, block, 0, stream, X, Wg, bg, Wf, bfv, Out);
}